// Round 14
// baseline (892.689 us; speedup 1.0000x reference)
//
#include <hip/hip_runtime.h>
#include <hip/hip_bf16.h>

typedef _Float16 f16;
typedef _Float16 half8 __attribute__((ext_vector_type(8)));
typedef _Float16 half4v __attribute__((ext_vector_type(4)));
typedef float f32x4 __attribute__((ext_vector_type(4)));
typedef float f32x16 __attribute__((ext_vector_type(16)));

#define B_ 4
#define S_ 3072
#define D_ 768
#define E_ 2000
#define NEG_INF -1.0e6f

// async global->LDS, 16B per lane; per-lane global src, linear LDS dest
#define GLD16(gsrc, ldst)                                                     \
  __builtin_amdgcn_global_load_lds(                                           \
      (const __attribute__((address_space(1))) void*)(gsrc),                  \
      (__attribute__((address_space(3))) void*)(ldst), 16, 0, 0)

// ---------------------------------------------------------------------------
// h [B,S,D] f32  ->  ht [B,D,S] f16   (LDS-tiled transpose, 64x64)
// ---------------------------------------------------------------------------
__global__ __launch_bounds__(256) void k_transpose(const float* __restrict__ h,
                                                   f16* __restrict__ ht) {
  __shared__ f16 tile[64][65];
  int b = blockIdx.z, s0 = blockIdx.x * 64, d0 = blockIdx.y * 64;
  int t = threadIdx.x, tx = t & 63, ty = t >> 6;
  const float* src = h + ((size_t)b * S_ + s0) * D_ + d0;
#pragma unroll
  for (int i = 0; i < 16; ++i) {
    int sl = i * 4 + ty;
    tile[sl][tx] = (f16)src[(size_t)sl * D_ + tx];
  }
  __syncthreads();
  f16* dst = ht + ((size_t)b * D_ + d0) * S_ + s0;
#pragma unroll
  for (int i = 0; i < 16; ++i) {
    int dl = i * 4 + ty;
    dst[(size_t)dl * S_ + tx] = tile[tx][dl];
  }
}

// ---------------------------------------------------------------------------
// z = tanh(h @ W^T + bias) -> zb f16 [B*S, D]
// ---------------------------------------------------------------------------
__global__ __launch_bounds__(256) void k_zgemm(const float* __restrict__ h,
                                               const float* __restrict__ W,
                                               const float* __restrict__ bias,
                                               f16* __restrict__ zb) {
  __shared__ f16 As[64][40];
  __shared__ f16 Bs[64][40];
  int i0 = blockIdx.x * 64, j0 = blockIdx.y * 64;
  int t = threadIdx.x, w = t >> 6, lane = t & 63, g = lane >> 4, li = lane & 15;
  int wi = w >> 1, wj = w & 1;

  f32x4 acc[2][2];
#pragma unroll
  for (int a = 0; a < 2; ++a)
#pragma unroll
    for (int b2 = 0; b2 < 2; ++b2) acc[a][b2] = (f32x4){0.f, 0.f, 0.f, 0.f};

  int srow = t >> 2, scol = (t & 3) * 8;
  const float* pA = h + (size_t)(i0 + srow) * D_ + scol;
  const float* pB = W + (size_t)(j0 + srow) * D_ + scol;

  for (int kc = 0; kc < D_; kc += 32) {
    float4 a0 = *(const float4*)(pA + kc);
    float4 a1 = *(const float4*)(pA + kc + 4);
    float4 b0 = *(const float4*)(pB + kc);
    float4 b1 = *(const float4*)(pB + kc + 4);
    half8 av = {(f16)a0.x, (f16)a0.y, (f16)a0.z, (f16)a0.w,
                (f16)a1.x, (f16)a1.y, (f16)a1.z, (f16)a1.w};
    half8 bv = {(f16)b0.x, (f16)b0.y, (f16)b0.z, (f16)b0.w,
                (f16)b1.x, (f16)b1.y, (f16)b1.z, (f16)b1.w};
    *(half8*)&As[srow][scol] = av;
    *(half8*)&Bs[srow][scol] = bv;
    __syncthreads();
#pragma unroll
    for (int it = 0; it < 2; ++it) {
      half8 af = *(const half8*)&As[wi * 32 + it * 16 + li][g * 8];
#pragma unroll
      for (int jt = 0; jt < 2; ++jt) {
        half8 bf = *(const half8*)&Bs[wj * 32 + jt * 16 + li][g * 8];
        acc[it][jt] =
            __builtin_amdgcn_mfma_f32_16x16x32_f16(af, bf, acc[it][jt], 0, 0, 0);
      }
    }
    __syncthreads();
  }
#pragma unroll
  for (int it = 0; it < 2; ++it) {
#pragma unroll
    for (int jt = 0; jt < 2; ++jt) {
      int jj = j0 + wj * 32 + jt * 16 + li;
      float bsv = bias[jj];
#pragma unroll
      for (int r = 0; r < 4; ++r) {
        int ii = i0 + wi * 32 + it * 16 + g * 4 + r;
        float v = acc[it][jt][r] + bsv;
        zb[(size_t)ii * D_ + jj] = (f16)tanhf(v);
      }
    }
  }
}

// ---------------------------------------------------------------------------
// Fused flash attention + head max-pool, v14: HALF-SIZE BLOCKS, 2 blocks/CU.
// 4 waves (256 thr), 32 q (8 labels), LDS 58.6 KB -> 2 independent blocks
// co-resident per CU (two barrier domains overlap each other's stalls).
// Regs: 256/wave bucket at 2 waves/SIMD; live ~210 -> no spill.
// Grid 1000 = 8 (b,qhalf swizzle) x 125.
//  seg1: mask ld | QK(i) 12 MFMA (4-way k-split, 192k/wave) | Cp[w] |
//        lgkm(0) bar B
//  seg2: K(i+1) DMA -> Ks | distributed softmax (8 q/wave, defer-max) ->
//        Pt/Fac/Rfl | Msk | lgkm(0) bar C
//  seg3: flag-gated rescale | V loads (192d slice) | PV 12 MFMA |
//        vmcnt(0) bar D   (K(i+1) landed; window = softmax+PV)
// ---------------------------------------------------------------------------
__global__ __launch_bounds__(256, 2)
void k_attn(const float* __restrict__ lf,
            const f16* __restrict__ zb,
            const f16* __restrict__ ht,
            const int* __restrict__ amask,
            float* __restrict__ out_m) {
  __shared__ __align__(16) char Lds[59920];
  char* KsB = Lds;                         // 49152: 32 rows x 1536B, swz (r&7)<<4
  char* CpB = Lds + 49152;                 // 4 slots x 2048 (slot = wave id)
  char* PtB = Lds + 57344;                 // 2048 (32 q rows x 64B)
  float* FacB = (float*)(Lds + 59392);     // 32 floats
  float* LfinB = (float*)(Lds + 59520);    // 32 floats
  int* MskI = (int*)(Lds + 59648);         // 2 x 32 ints
  int* RflW = (int*)(Lds + 59904);         // 4 per-wave rescale flags

  // ---- XCD-grouping swizzle: 1000 blocks = 8 x 125
  const int fid = blockIdx.x;
  const int x2 = fid & 7, u = fid >> 3;    // u: 0..124
  const int b = x2 >> 1;
  const int qtile = (x2 & 1) * 125 + u;    // 0..249
  const int q0 = qtile * 32;
  const int e0 = qtile * 8;

  const int t = threadIdx.x, w = t >> 6, l = t & 63;
  const int l31 = l & 31, h = l >> 5, h16 = h * 16;

  // ---- Q fragments (B operand): q = q0+l31, k = w*192 + kf*16 + h*8
  half8 qf[12];
  {
    const float* qp = lf + (size_t)(q0 + l31) * D_ + w * 192 + h * 8;
#pragma unroll
    for (int kf = 0; kf < 12; ++kf) {
      float4 v0 = *(const float4*)(qp + kf * 16);
      float4 v1 = *(const float4*)(qp + kf * 16 + 4);
      qf[kf] = (half8){(f16)v0.x, (f16)v0.y, (f16)v0.z, (f16)v0.w,
                       (f16)v1.x, (f16)v1.y, (f16)v1.z, (f16)v1.w};
    }
  }

  // ---- K staging: 12 chunks/thread; LDS linear dest, global pre-swizzled
  int klds[12], kgsw[12];
#pragma unroll
  for (int k = 0; k < 12; ++k) {
    int lin = (w * 12 + k) * 1024 + l * 16;
    int row = lin / 1536;
    int xo = lin - row * 1536;
    klds[k] = lin;
    kgsw[k] = row * 1536 + (xo ^ ((row & 7) << 4));
  }

  // ---- QK A(K)-frag base: s-row = l31, k = w*192 + kf*16 + h*8
  const int am7 = (l & 7) << 4;
  const int abase = l31 * 1536 + w * 384;

  // ---- row-swizzle for 64B-row buffers (Pt, Cp): ((row>>1)&3)<<4
  const int rswz = ((l31 >> 1) & 3) << 4;
  const int cqoff = l31 * 64;

  // ---- distributed-softmax role: wave owns 8 q = w*8 + (l>>3)
  const int qrow = w * 8 + (l >> 3);
  const int swzr = ((qrow >> 1) & 3) << 4;
  const int roff = qrow * 64 + ((8 * (l & 7)) ^ swzr);

  const char* zbB = (const char*)zb + (size_t)b * S_ * 1536;
  const f16* vbase = ht + ((size_t)b * D_ + w * 192 + l31) * S_ + h * 8;

  // ---- prologue: DMA K(0), mask(0)
#pragma unroll
  for (int k = 0; k < 12; ++k) GLD16(zbB + kgsw[k], KsB + klds[k]);
  if (t < 32) MskI[t] = amask[b * S_ + t];
  asm volatile("s_waitcnt vmcnt(0)" ::: "memory");
  __syncthreads();

  float mreg = -3.0e38f, lreg = 0.0f;
  f32x16 oacc[6];  // 32 q x 192 d (wave slice): 6 d-subtiles
#pragma unroll
  for (int d = 0; d < 6; ++d)
#pragma unroll
    for (int j = 0; j < 16; ++j) oacc[d][j] = 0.f;

  for (int i = 0; i < 96; ++i) {
    const int s0 = i * 32;
    const int s0n = (i < 95) ? s0 + 32 : 0;

    // ================= seg1 =================
    int mnext = (t < 32) ? amask[b * S_ + s0n + t] : 0;

    // QK(i): C[s32][q32], 12 MFMA over this wave's 192-k slice
    f32x16 ca;
#pragma unroll
    for (int j = 0; j < 16; ++j) ca[j] = 0.f;
    __builtin_amdgcn_s_setprio(1);
#pragma unroll
    for (int kf = 0; kf < 12; ++kf) {
      half8 a = *(const half8*)(KsB + abase + ((kf * 32 + h16) ^ am7));
      ca = __builtin_amdgcn_mfma_f32_32x32x16_f16(a, qf[kf], ca, 0, 0, 0);
    }
    __builtin_amdgcn_s_setprio(0);

    // all 4 waves write partials to Cp slot w
    {
      char* cp = CpB + w * 2048 + cqoff;
#pragma unroll
      for (int rr = 0; rr < 4; ++rr) {
        half4v pk = {(f16)ca[4 * rr], (f16)ca[4 * rr + 1], (f16)ca[4 * rr + 2],
                     (f16)ca[4 * rr + 3]};
        *(half4v*)(cp + ((rr * 16 + h * 8) ^ rswz)) = pk;
      }
    }
    asm volatile("s_waitcnt lgkmcnt(0)" ::: "memory");
    __builtin_amdgcn_s_barrier();  // bar B: Cp visible; QK reads of Ks done

    // ================= seg2 =================
    // K(i+1) DMA into single Ks (drained at bar D)
    {
      const char* src = zbB + (size_t)s0n * 1536;
#pragma unroll
      for (int k = 0; k < 12; ++k) GLD16(src + kgsw[k], KsB + klds[k]);
    }
    // distributed softmax: wave owns 8 q; 8 lanes per q cover 32 s
    {
      float p0 = 0.f, p1 = 0.f, p2 = 0.f, p3 = 0.f;
#pragma unroll
      for (int kk = 0; kk < 4; ++kk) {
        half4v pk = *(const half4v*)(CpB + kk * 2048 + roff);
        p0 += (float)pk[0];
        p1 += (float)pk[1];
        p2 += (float)pk[2];
        p3 += (float)pk[3];
      }
      int4 m4 = *(const int4*)(MskI + (i & 1) * 32 + 4 * (l & 7));
      if (!m4.x) p0 = NEG_INF;
      if (!m4.y) p1 = NEG_INF;
      if (!m4.z) p2 = NEG_INF;
      if (!m4.w) p3 = NEG_INF;
      float pmax = fmaxf(fmaxf(p0, p1), fmaxf(p2, p3));
      pmax = fmaxf(pmax, __shfl_xor(pmax, 1));
      pmax = fmaxf(pmax, __shfl_xor(pmax, 2));
      pmax = fmaxf(pmax, __shfl_xor(pmax, 4));
      // defer-max (T13, THR=8)
      int need = __any(pmax > mreg + 8.0f);
      float Mn = mreg, fec = 1.0f;
      if (need) {
        Mn = fmaxf(mreg, pmax);
        fec = __expf(mreg - Mn);
        mreg = Mn;
      }
      p0 = __expf(p0 - Mn);
      p1 = __expf(p1 - Mn);
      p2 = __expf(p2 - Mn);
      p3 = __expf(p3 - Mn);
      float ts = p0 + p1 + p2 + p3;
      ts += __shfl_xor(ts, 1);
      ts += __shfl_xor(ts, 2);
      ts += __shfl_xor(ts, 4);
      lreg = lreg * fec + ts;
      if ((l & 7) == 0) FacB[qrow] = fec;
      if (l == 0) RflW[w] = need;
      *(half4v*)(PtB + roff) = (half4v){(f16)p0, (f16)p1, (f16)p2, (f16)p3};
    }
    if (t < 32) MskI[((i + 1) & 1) * 32 + t] = mnext;
    asm volatile("s_waitcnt lgkmcnt(0)" ::: "memory");
    __builtin_amdgcn_s_barrier();  // bar C: Pt/Fac/Rfl/Msk visible

    // ================= seg3 =================
    {
      int4 fA = *(const int4*)RflW;
      int f0 = fA.x | fA.y | fA.z | fA.w;
      if (f0) {
        f32x4 frv[4];
#pragma unroll
        for (int rr = 0; rr < 4; ++rr)
          frv[rr] = *(const f32x4*)(FacB + rr * 8 + h * 4);
#pragma unroll
        for (int dt = 0; dt < 6; ++dt)
#pragma unroll
          for (int j = 0; j < 16; ++j) oacc[dt][j] *= frv[j >> 2][j & 3];
      }
      half8 pa0 = *(const half8*)(PtB + cqoff + (h16 ^ rswz));
      half8 pa1 = *(const half8*)(PtB + cqoff + ((32 + h16) ^ rswz));
      const f16* vp = vbase + s0;
      __builtin_amdgcn_s_setprio(1);
#pragma unroll
      for (int dt = 0; dt < 6; ++dt) {
        half8 v0 = *(const half8*)(vp + (size_t)dt * 32 * S_);
        half8 v1 = *(const half8*)(vp + (size_t)dt * 32 * S_ + 16);
        oacc[dt] =
            __builtin_amdgcn_mfma_f32_32x32x16_f16(pa0, v0, oacc[dt], 0, 0, 0);
        oacc[dt] =
            __builtin_amdgcn_mfma_f32_32x32x16_f16(pa1, v1, oacc[dt], 0, 0, 0);
      }
      __builtin_amdgcn_s_setprio(0);
    }
    asm volatile("s_waitcnt vmcnt(0)" ::: "memory");  // K(i+1) landed
    __builtin_amdgcn_s_barrier();  // bar D
  }

  if ((l & 7) == 0) LfinB[qrow] = lreg;
  __syncthreads();

  // ---- epilogue: O/l, head max-pool (head = reg&3), store ----
  f32x4 rlv[4];
#pragma unroll
  for (int rr = 0; rr < 4; ++rr) {
    f32x4 lv = *(const f32x4*)(LfinB + rr * 8 + h * 4);
    rlv[rr] = (f32x4){1.0f / lv[0], 1.0f / lv[1], 1.0f / lv[2], 1.0f / lv[3]};
  }
#pragma unroll
  for (int dt = 0; dt < 6; ++dt)
#pragma unroll
    for (int rr = 0; rr < 4; ++rr) {
      float mv = oacc[dt][4 * rr + 0] * rlv[rr][0];
      mv = fmaxf(mv, oacc[dt][4 * rr + 1] * rlv[rr][1]);
      mv = fmaxf(mv, oacc[dt][4 * rr + 2] * rlv[rr][2]);
      mv = fmaxf(mv, oacc[dt][4 * rr + 3] * rlv[rr][3]);
      int e_loc = rr * 2 + h;
      out_m[((size_t)b * E_ + e0 + e_loc) * D_ + w * 192 + dt * 32 + l31] = mv;
    }
}

// ---------------------------------------------------------------------------
// logits[b,e] = sum_d cls_w[e,d]*m[b,e,d] + cls_b[e]; one wave per (b,e)
// ---------------------------------------------------------------------------
__global__ __launch_bounds__(256) void k_logits(const float* __restrict__ cw,
                                                const float* __restrict__ cb,
                                                const float* __restrict__ m,
                                                float* __restrict__ out) {
  int t = threadIdx.x, w = t >> 6, lane = t & 63;
  int rid = blockIdx.x * 4 + w;  // 0..7999
  int b = rid / E_, e = rid - b * E_;
  const float* mr = m + (size_t)rid * D_;
  const float* cr = cw + (size_t)e * D_;
  float acc = 0.f;
#pragma unroll
  for (int i = 0; i < 12; ++i) acc += cr[i * 64 + lane] * mr[i * 64 + lane];
#pragma unroll
  for (int off = 32; off >= 1; off >>= 1) acc += __shfl_xor(acc, off);
  if (lane == 0) out[rid] = acc + cb[e];
}

// ---------------------------------------------------------------------------
extern "C" void kernel_launch(void* const* d_in, const int* in_sizes, int n_in,
                              void* d_out, int out_size, void* d_ws, size_t ws_size,
                              hipStream_t stream) {
  const float* h = (const float*)d_in[0];
  const int* amask = (const int*)d_in[1];
  const float* lf = (const float*)d_in[2];
  const float* Ww = (const float*)d_in[3];
  const float* Wb = (const float*)d_in[4];
  const float* cw = (const float*)d_in[5];
  const float* cb = (const float*)d_in[6];
  float* out = (float*)d_out;

  f16* zb = (f16*)d_ws;                     // 12288*768*2 = 18874368 B
  f16* ht = (f16*)((char*)d_ws + 18874368); // 4*768*3072*2 = 18874368 B

  k_transpose<<<dim3(48, 12, 4), 256, 0, stream>>>(h, ht);
  k_zgemm<<<dim3(192, 12), 256, 0, stream>>>(h, Ww, Wb, zb);
  k_attn<<<1000, 256, 0, stream>>>(lf, zb, ht, amask, out + 8000);
  k_logits<<<2000, 256, 0, stream>>>(cw, cb, out + 8000, out);
}

// Round 15
// 774.357 us; speedup vs baseline: 1.1528x; 1.1528x over previous
//
#include <hip/hip_runtime.h>
#include <hip/hip_bf16.h>

typedef _Float16 f16;
typedef _Float16 half8 __attribute__((ext_vector_type(8)));
typedef _Float16 half4v __attribute__((ext_vector_type(4)));
typedef float f32x4 __attribute__((ext_vector_type(4)));
typedef float f32x16 __attribute__((ext_vector_type(16)));

#define B_ 4
#define S_ 3072
#define D_ 768
#define E_ 2000
#define NEG_INF -1.0e6f

// async global->LDS, 16B per lane; per-lane global src, linear LDS dest
#define GLD16(gsrc, ldst)                                                     \
  __builtin_amdgcn_global_load_lds(                                           \
      (const __attribute__((address_space(1))) void*)(gsrc),                  \
      (__attribute__((address_space(3))) void*)(ldst), 16, 0, 0)

// ---------------------------------------------------------------------------
// h [B,S,D] f32  ->  ht [B,D,S] f16   (LDS-tiled transpose, 64x64)
// ---------------------------------------------------------------------------
__global__ __launch_bounds__(256) void k_transpose(const float* __restrict__ h,
                                                   f16* __restrict__ ht) {
  __shared__ f16 tile[64][65];
  int b = blockIdx.z, s0 = blockIdx.x * 64, d0 = blockIdx.y * 64;
  int t = threadIdx.x, tx = t & 63, ty = t >> 6;
  const float* src = h + ((size_t)b * S_ + s0) * D_ + d0;
#pragma unroll
  for (int i = 0; i < 16; ++i) {
    int sl = i * 4 + ty;
    tile[sl][tx] = (f16)src[(size_t)sl * D_ + tx];
  }
  __syncthreads();
  f16* dst = ht + ((size_t)b * D_ + d0) * S_ + s0;
#pragma unroll
  for (int i = 0; i < 16; ++i) {
    int dl = i * 4 + ty;
    dst[(size_t)dl * S_ + tx] = tile[tx][dl];
  }
}

// ---------------------------------------------------------------------------
// z = tanh(h @ W^T + bias) -> zb f16 [B*S, D]
// ---------------------------------------------------------------------------
__global__ __launch_bounds__(256) void k_zgemm(const float* __restrict__ h,
                                               const float* __restrict__ W,
                                               const float* __restrict__ bias,
                                               f16* __restrict__ zb) {
  __shared__ f16 As[64][40];
  __shared__ f16 Bs[64][40];
  int i0 = blockIdx.x * 64, j0 = blockIdx.y * 64;
  int t = threadIdx.x, w = t >> 6, lane = t & 63, g = lane >> 4, li = lane & 15;
  int wi = w >> 1, wj = w & 1;

  f32x4 acc[2][2];
#pragma unroll
  for (int a = 0; a < 2; ++a)
#pragma unroll
    for (int b2 = 0; b2 < 2; ++b2) acc[a][b2] = (f32x4){0.f, 0.f, 0.f, 0.f};

  int srow = t >> 2, scol = (t & 3) * 8;
  const float* pA = h + (size_t)(i0 + srow) * D_ + scol;
  const float* pB = W + (size_t)(j0 + srow) * D_ + scol;

  for (int kc = 0; kc < D_; kc += 32) {
    float4 a0 = *(const float4*)(pA + kc);
    float4 a1 = *(const float4*)(pA + kc + 4);
    float4 b0 = *(const float4*)(pB + kc);
    float4 b1 = *(const float4*)(pB + kc + 4);
    half8 av = {(f16)a0.x, (f16)a0.y, (f16)a0.z, (f16)a0.w,
                (f16)a1.x, (f16)a1.y, (f16)a1.z, (f16)a1.w};
    half8 bv = {(f16)b0.x, (f16)b0.y, (f16)b0.z, (f16)b0.w,
                (f16)b1.x, (f16)b1.y, (f16)b1.z, (f16)b1.w};
    *(half8*)&As[srow][scol] = av;
    *(half8*)&Bs[srow][scol] = bv;
    __syncthreads();
#pragma unroll
    for (int it = 0; it < 2; ++it) {
      half8 af = *(const half8*)&As[wi * 32 + it * 16 + li][g * 8];
#pragma unroll
      for (int jt = 0; jt < 2; ++jt) {
        half8 bf = *(const half8*)&Bs[wj * 32 + jt * 16 + li][g * 8];
        acc[it][jt] =
            __builtin_amdgcn_mfma_f32_16x16x32_f16(af, bf, acc[it][jt], 0, 0, 0);
      }
    }
    __syncthreads();
  }
#pragma unroll
  for (int it = 0; it < 2; ++it) {
#pragma unroll
    for (int jt = 0; jt < 2; ++jt) {
      int jj = j0 + wj * 32 + jt * 16 + li;
      float bsv = bias[jj];
#pragma unroll
      for (int r = 0; r < 4; ++r) {
        int ii = i0 + wi * 32 + it * 16 + g * 4 + r;
        float v = acc[it][jt][r] + bsv;
        zb[(size_t)ii * D_ + jj] = (f16)tanhf(v);
      }
    }
  }
}

// ---------------------------------------------------------------------------
// Fused flash attention + head max-pool, v15 = v13 champion + dual-chain QK
// + K double-buffer (DMA issued post-QK in seg1, drained at bar C).
// 8 waves (512 thr), 64 q, 32-key tiles, 2 raw barriers/iter, 1 block/CU.
//  seg1: mask ld | PV(i-1){flag-gated rescale, Pt, Vb} | V(i)->reg issue |
//        QK(i) 2x6 MFMA chains from Ks[cur] | K(i+1) DMA -> Ks[nxt] |
//        Cp[w] | lgkm(0) bar B
//  seg2: distributed softmax (8 q/wave, defer-max THR=8) -> Pt/Fac/Rfl |
//        Msk | vmcnt(0) lgkm(0) bar C  (V+K all landed; K window ~600cyc)
// ---------------------------------------------------------------------------
__global__ __launch_bounds__(512)
__attribute__((amdgpu_waves_per_eu(2, 2)))
void k_attn(const float* __restrict__ lf,
            const f16* __restrict__ zb,
            const f16* __restrict__ ht,
            const int* __restrict__ amask,
            float* __restrict__ out_m) {
  __shared__ __align__(16) char Lds[119584];
  char* KsB = Lds;                         // 2 x 49152: 32 rows x 1536B, swz (r&7)<<4
  char* CpB = Lds + 98304;                 // 8 slots x 2048 (slot = wave id)
  char* PtB = Lds + 114688;                // 2 x 2048 (P by q-half)
  float* FacB = (float*)(Lds + 118784);    // 64 floats
  float* LfinB = (float*)(Lds + 119040);   // 64 floats
  int* MskI = (int*)(Lds + 119296);        // 2 x 32 ints
  int* RflW = (int*)(Lds + 119552);        // 8 per-wave rescale flags

  // ---- XCD-grouping swizzle (grid = 512 flat, 12 dead blocks)
  const int fid = blockIdx.x;
  const int x2 = fid & 7, u = fid >> 3;
  const int b = x2 >> 1;
  const int qtile = (x2 & 1) * 64 + u;
  if (qtile >= 125) return;
  const int q0 = qtile * 64;
  const int e0 = qtile * 16;

  const int t = threadIdx.x, w = t >> 6, l = t & 63;
  const int l31 = l & 31, h = l >> 5, h16 = h * 16;
  const int qh = w & 1, kq = w >> 1;  // QK roles
  const int dh = w;                   // PV role: 96-d slice

  // ---- Q fragments (B operand): q = q0+qh*32+l31, k = kq*192+kf*16+h*8
  half8 qf[12];
  {
    const float* qp = lf + (size_t)(q0 + qh * 32 + l31) * D_ + kq * 192 + h * 8;
#pragma unroll
    for (int kf = 0; kf < 12; ++kf) {
      float4 v0 = *(const float4*)(qp + kf * 16);
      float4 v1 = *(const float4*)(qp + kf * 16 + 4);
      qf[kf] = (half8){(f16)v0.x, (f16)v0.y, (f16)v0.z, (f16)v0.w,
                       (f16)v1.x, (f16)v1.y, (f16)v1.z, (f16)v1.w};
    }
  }

  // ---- K staging: LDS linear dest, global source pre-swizzled
  int klds[6], kgsw[6];
#pragma unroll
  for (int k = 0; k < 6; ++k) {
    int lin = (w * 6 + k) * 1024 + l * 16;
    int row = lin / 1536;
    int xo = lin - row * 1536;
    klds[k] = lin;
    kgsw[k] = row * 1536 + (xo ^ ((row & 7) << 4));
  }

  // ---- QK A(K)-frag base: s-row = l31, k = kq*192 + kf*16 + h*8
  const int am7 = (l & 7) << 4;
  const int abase = l31 * 1536 + kq * 384;

  // ---- row-swizzle for 64B-row buffers (Pt, Cp): ((row>>1)&3)<<4
  const int rswz = ((l31 >> 1) & 3) << 4;
  const int cqoff = l31 * 64;

  // ---- distributed-softmax role: wave handles 8 q = qh_s*32 + qoct*8+(l>>3)
  const int qh_s = w >> 2, qoct = w & 3;
  const int qrow = qoct * 8 + (l >> 3);
  const int swzr = ((qrow >> 1) & 3) << 4;
  const int roff = qrow * 64 + ((8 * (l & 7)) ^ swzr);
  const int qabs = qh_s * 32 + qrow;

  const char* zbB = (const char*)zb + (size_t)b * S_ * 1536;
  const f16* vbase = ht + ((size_t)b * D_ + dh * 96 + l31) * S_ + h * 8;

  // ---- prologue: DMA K(0) -> buf0, mask(0)
#pragma unroll
  for (int k = 0; k < 6; ++k) GLD16(zbB + kgsw[k], KsB + klds[k]);
  if (t < 32) MskI[t] = amask[b * S_ + t];
  asm volatile("s_waitcnt vmcnt(0)" ::: "memory");
  __syncthreads();

  float mreg = -3.0e38f, lreg = 0.0f;
  f32x16 oacc[2][3];
#pragma unroll
  for (int a = 0; a < 2; ++a)
#pragma unroll
    for (int d = 0; d < 3; ++d)
#pragma unroll
      for (int j = 0; j < 16; ++j) oacc[a][d][j] = 0.f;

  half8 Vb[6];  // per-wave V slice, single-buffered across iterations

  for (int i = 0; i < 96; ++i) {
    const int s0 = i * 32;
    const int s0n = (i < 95) ? s0 + 32 : 0;
    const char* ksC = KsB + (i & 1) * 49152;
    char* ksN = KsB + ((i & 1) ^ 1) * 49152;

    // ================= seg1 =================
    int mnext = (t < 32) ? amask[b * S_ + s0n + t] : 0;

    // PV(i-1): flag-gated rescale + MFMA (P from LDS, V from regs)
    if (i > 0) {
      int4 fA = *(const int4*)RflW;
      int4 fB = *(const int4*)(RflW + 4);
      int f0 = fA.x | fA.y | fA.z | fA.w;
      int f1 = fB.x | fB.y | fB.z | fB.w;
      if (f0) {
        f32x4 frv[4];
#pragma unroll
        for (int rr = 0; rr < 4; ++rr)
          frv[rr] = *(const f32x4*)(FacB + rr * 8 + h * 4);
#pragma unroll
        for (int dt = 0; dt < 3; ++dt)
#pragma unroll
          for (int j = 0; j < 16; ++j) oacc[0][dt][j] *= frv[j >> 2][j & 3];
      }
      if (f1) {
        f32x4 frv[4];
#pragma unroll
        for (int rr = 0; rr < 4; ++rr)
          frv[rr] = *(const f32x4*)(FacB + 32 + rr * 8 + h * 4);
#pragma unroll
        for (int dt = 0; dt < 3; ++dt)
#pragma unroll
          for (int j = 0; j < 16; ++j) oacc[1][dt][j] *= frv[j >> 2][j & 3];
      }
      half8 pa[2][2];
#pragma unroll
      for (int q2 = 0; q2 < 2; ++q2)
#pragma unroll
        for (int ss = 0; ss < 2; ++ss)
          pa[q2][ss] = *(const half8*)(PtB + q2 * 2048 + cqoff +
                                       ((ss * 32 + h16) ^ rswz));
      __builtin_amdgcn_s_setprio(1);
#pragma unroll
      for (int dt = 0; dt < 3; ++dt)
#pragma unroll
        for (int ss = 0; ss < 2; ++ss)
#pragma unroll
          for (int q2 = 0; q2 < 2; ++q2)
            oacc[q2][dt] = __builtin_amdgcn_mfma_f32_32x32x16_f16(
                pa[q2][ss], Vb[dt * 2 + ss], oacc[q2][dt], 0, 0, 0);
      __builtin_amdgcn_s_setprio(0);
    }

    // issue V(i) -> regs (WAR on Vb orders this after PV(i-1))
    {
      const f16* vp = vbase + s0;
#pragma unroll
      for (int dt = 0; dt < 3; ++dt)
#pragma unroll
        for (int ss = 0; ss < 2; ++ss)
          Vb[dt * 2 + ss] = *(const half8*)(vp + (size_t)dt * 32 * S_ + ss * 16);
    }

    // QK(i): C[s32][q32], DUAL chains (halved dependent-latency)
    f32x16 ca, cb2;
#pragma unroll
    for (int j = 0; j < 16; ++j) { ca[j] = 0.f; cb2[j] = 0.f; }
    __builtin_amdgcn_s_setprio(1);
#pragma unroll
    for (int kf = 0; kf < 6; ++kf) {
      half8 a0 = *(const half8*)(ksC + abase + ((kf * 32 + h16) ^ am7));
      half8 a1 = *(const half8*)(ksC + abase + (((kf + 6) * 32 + h16) ^ am7));
      ca = __builtin_amdgcn_mfma_f32_32x32x16_f16(a0, qf[kf], ca, 0, 0, 0);
      cb2 = __builtin_amdgcn_mfma_f32_32x32x16_f16(a1, qf[kf + 6], cb2, 0, 0, 0);
    }
    __builtin_amdgcn_s_setprio(0);
#pragma unroll
    for (int j = 0; j < 16; ++j) ca[j] += cb2[j];

    // K(i+1) DMA -> Ks[nxt] (post-QK: short addr live-ranges; drains at bar C)
    __builtin_amdgcn_sched_barrier(0);
    {
      const char* src = zbB + (size_t)s0n * 1536;
#pragma unroll
      for (int k = 0; k < 6; ++k) GLD16(src + kgsw[k], ksN + klds[k]);
    }

    // ALL waves write partials to Cp slot w
    {
      char* cp = CpB + w * 2048 + cqoff;
#pragma unroll
      for (int rr = 0; rr < 4; ++rr) {
        half4v pk = {(f16)ca[4 * rr], (f16)ca[4 * rr + 1], (f16)ca[4 * rr + 2],
                     (f16)ca[4 * rr + 3]};
        *(half4v*)(cp + ((rr * 16 + h * 8) ^ rswz)) = pk;
      }
    }
    asm volatile("s_waitcnt lgkmcnt(0)" ::: "memory");
    __builtin_amdgcn_s_barrier();  // bar B: all Cp partials visible

    // ================= seg2: distributed softmax =================
    {
      float p0 = 0.f, p1 = 0.f, p2 = 0.f, p3 = 0.f;
#pragma unroll
      for (int kk = 0; kk < 4; ++kk) {
        half4v pk = *(const half4v*)(CpB + (kk * 2 + qh_s) * 2048 + roff);
        p0 += (float)pk[0];
        p1 += (float)pk[1];
        p2 += (float)pk[2];
        p3 += (float)pk[3];
      }
      int4 m4 = *(const int4*)(MskI + (i & 1) * 32 + 4 * (l & 7));
      if (!m4.x) p0 = NEG_INF;
      if (!m4.y) p1 = NEG_INF;
      if (!m4.z) p2 = NEG_INF;
      if (!m4.w) p3 = NEG_INF;
      float pmax = fmaxf(fmaxf(p0, p1), fmaxf(p2, p3));
      pmax = fmaxf(pmax, __shfl_xor(pmax, 1));
      pmax = fmaxf(pmax, __shfl_xor(pmax, 2));
      pmax = fmaxf(pmax, __shfl_xor(pmax, 4));
      // defer-max (T13, THR=8)
      int need = __any(pmax > mreg + 8.0f);
      float Mn = mreg, fec = 1.0f;
      if (need) {
        Mn = fmaxf(mreg, pmax);
        fec = __expf(mreg - Mn);
        mreg = Mn;
      }
      p0 = __expf(p0 - Mn);
      p1 = __expf(p1 - Mn);
      p2 = __expf(p2 - Mn);
      p3 = __expf(p3 - Mn);
      float ts = p0 + p1 + p2 + p3;
      ts += __shfl_xor(ts, 1);
      ts += __shfl_xor(ts, 2);
      ts += __shfl_xor(ts, 4);
      lreg = lreg * fec + ts;
      if ((l & 7) == 0) FacB[qabs] = fec;
      if (l == 0) RflW[w] = need;
      *(half4v*)(PtB + qh_s * 2048 + roff) =
          (half4v){(f16)p0, (f16)p1, (f16)p2, (f16)p3};
    }
    if (t < 32) MskI[((i + 1) & 1) * 32 + t] = mnext;
    asm volatile("s_waitcnt vmcnt(0) lgkmcnt(0)" ::: "memory");
    __builtin_amdgcn_s_barrier();  // bar C: Pt/Fac/Rfl/Msk/Ks[nxt]/Vb ready
  }

  // ---- final PV (tile 95) ----
  {
    int4 fA = *(const int4*)RflW;
    int4 fB = *(const int4*)(RflW + 4);
    int f0 = fA.x | fA.y | fA.z | fA.w;
    int f1 = fB.x | fB.y | fB.z | fB.w;
    if (f0) {
      f32x4 frv[4];
#pragma unroll
      for (int rr = 0; rr < 4; ++rr)
        frv[rr] = *(const f32x4*)(FacB + rr * 8 + h * 4);
#pragma unroll
      for (int dt = 0; dt < 3; ++dt)
#pragma unroll
        for (int j = 0; j < 16; ++j) oacc[0][dt][j] *= frv[j >> 2][j & 3];
    }
    if (f1) {
      f32x4 frv[4];
#pragma unroll
      for (int rr = 0; rr < 4; ++rr)
        frv[rr] = *(const f32x4*)(FacB + 32 + rr * 8 + h * 4);
#pragma unroll
      for (int dt = 0; dt < 3; ++dt)
#pragma unroll
        for (int j = 0; j < 16; ++j) oacc[1][dt][j] *= frv[j >> 2][j & 3];
    }
    half8 pa[2][2];
#pragma unroll
    for (int q2 = 0; q2 < 2; ++q2)
#pragma unroll
      for (int ss = 0; ss < 2; ++ss)
        pa[q2][ss] = *(const half8*)(PtB + q2 * 2048 + cqoff +
                                     ((ss * 32 + h16) ^ rswz));
#pragma unroll
    for (int dt = 0; dt < 3; ++dt)
#pragma unroll
      for (int ss = 0; ss < 2; ++ss)
#pragma unroll
        for (int q2 = 0; q2 < 2; ++q2)
          oacc[q2][dt] = __builtin_amdgcn_mfma_f32_32x32x16_f16(
              pa[q2][ss], Vb[dt * 2 + ss], oacc[q2][dt], 0, 0, 0);
  }

  if ((l & 7) == 0) LfinB[qabs] = lreg;
  __syncthreads();

  // ---- epilogue: O/l, head max-pool (head = reg&3), store ----
  f32x4 rlv[2][4];
#pragma unroll
  for (int q2 = 0; q2 < 2; ++q2)
#pragma unroll
    for (int rr = 0; rr < 4; ++rr) {
      f32x4 lv = *(const f32x4*)(LfinB + q2 * 32 + rr * 8 + h * 4);
      rlv[q2][rr] =
          (f32x4){1.0f / lv[0], 1.0f / lv[1], 1.0f / lv[2], 1.0f / lv[3]};
    }
#pragma unroll
  for (int q2 = 0; q2 < 2; ++q2)
#pragma unroll
    for (int dt = 0; dt < 3; ++dt)
#pragma unroll
      for (int rr = 0; rr < 4; ++rr) {
        float mv = oacc[q2][dt][4 * rr + 0] * rlv[q2][rr][0];
        mv = fmaxf(mv, oacc[q2][dt][4 * rr + 1] * rlv[q2][rr][1]);
        mv = fmaxf(mv, oacc[q2][dt][4 * rr + 2] * rlv[q2][rr][2]);
        mv = fmaxf(mv, oacc[q2][dt][4 * rr + 3] * rlv[q2][rr][3]);
        int e_loc = q2 * 8 + rr * 2 + h;
        out_m[((size_t)b * E_ + e0 + e_loc) * D_ + dh * 96 + dt * 32 + l31] = mv;
      }
}

// ---------------------------------------------------------------------------
// logits[b,e] = sum_d cls_w[e,d]*m[b,e,d] + cls_b[e]; one wave per (b,e)
// ---------------------------------------------------------------------------
__global__ __launch_bounds__(256) void k_logits(const float* __restrict__ cw,
                                                const float* __restrict__ cb,
                                                const float* __restrict__ m,
                                                float* __restrict__ out) {
  int t = threadIdx.x, w = t >> 6, lane = t & 63;
  int rid = blockIdx.x * 4 + w;  // 0..7999
  int b = rid / E_, e = rid - b * E_;
  const float* mr = m + (size_t)rid * D_;
  const float* cr = cw + (size_t)e * D_;
  float acc = 0.f;
#pragma unroll
  for (int i = 0; i < 12; ++i) acc += cr[i * 64 + lane] * mr[i * 64 + lane];
#pragma unroll
  for (int off = 32; off >= 1; off >>= 1) acc += __shfl_xor(acc, off);
  if (lane == 0) out[rid] = acc + cb[e];
}

// ---------------------------------------------------------------------------
extern "C" void kernel_launch(void* const* d_in, const int* in_sizes, int n_in,
                              void* d_out, int out_size, void* d_ws, size_t ws_size,
                              hipStream_t stream) {
  const float* h = (const float*)d_in[0];
  const int* amask = (const int*)d_in[1];
  const float* lf = (const float*)d_in[2];
  const float* Ww = (const float*)d_in[3];
  const float* Wb = (const float*)d_in[4];
  const float* cw = (const float*)d_in[5];
  const float* cb = (const float*)d_in[6];
  float* out = (float*)d_out;

  f16* zb = (f16*)d_ws;                     // 12288*768*2 = 18874368 B
  f16* ht = (f16*)((char*)d_ws + 18874368); // 4*768*3072*2 = 18874368 B

  k_transpose<<<dim3(48, 12, 4), 256, 0, stream>>>(h, ht);
  k_zgemm<<<dim3(192, 12), 256, 0, stream>>>(h, Ww, Wb, zb);
  k_attn<<<512, 512, 0, stream>>>(lf, zb, ht, amask, out + 8000);
  k_logits<<<2000, 256, 0, stream>>>(cw, cb, out + 8000, out);
}